// Round 6
// baseline (213.896 us; speedup 1.0000x reference)
//
#include <hip/hip_runtime.h>

#define N_NODES 100000
#define NUM_TYPES 8
#define FACTOR 0.125f      // 1/sqrt(64)

#define S_CHUNK 20224      // nodes per chunk; 20224*4B = 80 896 B bins
                           // +256B scales -> 81 408 B, rounds to <= 81 920 B (80 KB)
                           // => 2 blocks/CU fit the 160 KB LDS pool exactly
#define C_CHUNKS 5         // 5*20224 = 101 120 >= 100 000
#define THR 1024
#define B_TARGET 102       // grid = 5*102 = 510 blocks ~= 2/CU

// Fused chunk-sum. Block (c,b): scans edge segment b; edges whose center lies in
// chunk c gather the two atom types, apply the scale, accumulate into 80KB LDS
// bins. Type gathers happen exactly once per edge across the grid (guarded).
// c = blockIdx % 5 -> the 5 chunks of a segment dispatch adjacently and sweep
// the SAME edge cache lines simultaneously (L2/L3 absorbs the 5x logical re-read).
// 2 blocks/CU (~26 waves) overlap gather latency against the LDS-atomic pipe.
__global__ __launch_bounds__(THR, 8) void fused_chunk_sum_kernel(
    const int* __restrict__ centers,
    const int* __restrict__ neighbors,
    const float* __restrict__ eng,
    const int* __restrict__ atom_type,
    const float* __restrict__ scales,
    float* __restrict__ partials,          // [C_CHUNKS][B][S_CHUNK]
    int E, int B)
{
    __shared__ __align__(16) float bins[S_CHUNK];
    __shared__ float s_scales[NUM_TYPES * NUM_TYPES];

    const int c = blockIdx.x % C_CHUNKS;   // chunk (fast-varying -> co-scheduled)
    const int b = blockIdx.x / C_CHUNKS;   // edge segment

    if (threadIdx.x < NUM_TYPES * NUM_TYPES)
        s_scales[threadIdx.x] = scales[threadIdx.x] * FACTOR;   // fold FACTOR

    float4* bins4 = (float4*)bins;
    for (int j = threadIdx.x; j < S_CHUNK / 4; j += THR)
        bins4[j] = make_float4(0.f, 0.f, 0.f, 0.f);
    __syncthreads();

    const int base = c * S_CHUNK;
    const int n4 = E >> 2;

    for (int i = b * THR + (int)threadIdx.x; i < n4; i += B * THR) {
        int4   cc = ((const int4*)centers)[i];
        int4   nn = ((const int4*)neighbors)[i];
        float4 e  = ((const float4*)eng)[i];

        unsigned j0 = (unsigned)(cc.x - base);
        unsigned j1 = (unsigned)(cc.y - base);
        unsigned j2 = (unsigned)(cc.z - base);
        unsigned j3 = (unsigned)(cc.w - base);

        if (j0 < S_CHUNK)
            atomicAdd(&bins[j0], e.x * s_scales[atom_type[cc.x] * NUM_TYPES + atom_type[nn.x]]);
        if (j1 < S_CHUNK)
            atomicAdd(&bins[j1], e.y * s_scales[atom_type[cc.y] * NUM_TYPES + atom_type[nn.y]]);
        if (j2 < S_CHUNK)
            atomicAdd(&bins[j2], e.z * s_scales[atom_type[cc.z] * NUM_TYPES + atom_type[nn.z]]);
        if (j3 < S_CHUNK)
            atomicAdd(&bins[j3], e.w * s_scales[atom_type[cc.w] * NUM_TYPES + atom_type[nn.w]]);
    }

    // tail (E % 4) — dead for E = 6,400,000; handled by segment b==0 of each chunk
    if (b == 0) {
        for (int i = (n4 << 2) + (int)threadIdx.x; i < E; i += THR) {
            int cn = centers[i];
            unsigned j = (unsigned)(cn - base);
            if (j < S_CHUNK)
                atomicAdd(&bins[j], eng[i] * s_scales[atom_type[cn] * NUM_TYPES + atom_type[neighbors[i]]]);
        }
    }

    __syncthreads();
    float4* dst4 = (float4*)(partials + ((size_t)c * B + b) * S_CHUNK);
    for (int j = threadIdx.x; j < S_CHUNK / 4; j += THR) dst4[j] = bins4[j];
}

// out[4t..4t+3] = sum over B segment-partials (float4; chunk rows are 4-aligned,
// S_CHUNK % 4 == 0 so a float4 never straddles a chunk boundary).
__global__ __launch_bounds__(256) void reduce_kernel(
    const float* __restrict__ partials, float* __restrict__ out, int B, int N4)
{
    int t = blockIdx.x * blockDim.x + threadIdx.x;
    if (t >= N4) return;
    int n = t * 4;
    int c = n / S_CHUNK;
    int j = n - c * S_CHUNK;
    const float4* p = (const float4*)(partials + ((size_t)c * B) * S_CHUNK + j);
    float4 s = make_float4(0.f, 0.f, 0.f, 0.f);
    for (int b = 0; b < B; ++b) {
        float4 v = p[(size_t)b * (S_CHUNK / 4)];
        s.x += v.x; s.y += v.y; s.z += v.z; s.w += v.w;
    }
    ((float4*)out)[t] = s;
}

// Scalar reduce fallback for N % 4 != 0.
__global__ __launch_bounds__(256) void reduce_scalar_kernel(
    const float* __restrict__ partials, float* __restrict__ out, int B, int N)
{
    int n = blockIdx.x * blockDim.x + threadIdx.x;
    if (n >= N) return;
    int c = n / S_CHUNK;
    int j = n - c * S_CHUNK;
    const float* p = partials + ((size_t)c * B) * S_CHUNK + j;
    float s = 0.0f;
    for (int b = 0; b < B; ++b) s += p[(size_t)b * S_CHUNK];
    out[n] = s;
}

// Fallback (tiny workspace only): direct atomic scatter into out.
__global__ __launch_bounds__(256) void edge_sum_atomic_kernel(
    const int* __restrict__ centers, const int* __restrict__ neighbors,
    const float* __restrict__ eng, const int* __restrict__ atom_type,
    const float* __restrict__ scales, float* __restrict__ out, int E)
{
    __shared__ float s_scales[NUM_TYPES * NUM_TYPES];
    if (threadIdx.x < NUM_TYPES * NUM_TYPES) s_scales[threadIdx.x] = scales[threadIdx.x];
    __syncthreads();
    int tid = blockIdx.x * blockDim.x + threadIdx.x;
    int stride = gridDim.x * blockDim.x;
    for (int i = tid; i < E; i += stride) {
        int cn = centers[i];
        float v = eng[i] * s_scales[atom_type[cn] * NUM_TYPES + atom_type[neighbors[i]]] * FACTOR;
        unsafeAtomicAdd(&out[cn], v);
    }
}

extern "C" void kernel_launch(void* const* d_in, const int* in_sizes, int n_in,
                              void* d_out, int out_size, void* d_ws, size_t ws_size,
                              hipStream_t stream) {
    const int E = in_sizes[1];  // edge_eng element count
    const int N = in_sizes[2];  // atom_type element count
    const int* edge_index = (const int*)d_in[0];   // [2, E]
    const float* edge_eng = (const float*)d_in[1]; // [E, 1]
    const int* atom_type = (const int*)d_in[2];    // [N, 1]
    const float* scales = (const float*)d_in[3];   // [T, T]
    float* out = (float*)d_out;

    const int* centers = edge_index;
    const int* neighbors = edge_index + E;

    // Workspace: C * B * S_CHUNK floats (B=102 -> 41.3 MB). Shrink B if ws small.
    size_t per_b = (size_t)C_CHUNKS * S_CHUNK * sizeof(float);  // 404 480 B per segment
    int B = (int)(ws_size / per_b);
    if (B > B_TARGET) B = B_TARGET;

    if (N <= C_CHUNKS * S_CHUNK && B >= 8) {
        float* partials = (float*)d_ws;
        // No memset needed: every block writes its full bin array.
        fused_chunk_sum_kernel<<<C_CHUNKS * B, THR, 0, stream>>>(
            centers, neighbors, edge_eng, atom_type, scales, partials, E, B);
        if ((N & 3) == 0)
            reduce_kernel<<<(N / 4 + 255) / 256, 256, 0, stream>>>(partials, out, B, N / 4);
        else
            reduce_scalar_kernel<<<(N + 255) / 256, 256, 0, stream>>>(partials, out, B, N);
    } else {
        hipMemsetAsync(d_out, 0, (size_t)out_size * sizeof(float), stream);
        edge_sum_atomic_kernel<<<2048, 256, 0, stream>>>(
            centers, neighbors, edge_eng, atom_type, scales, out, E);
    }
}

// Round 7
// 206.040 us; speedup vs baseline: 1.0381x; 1.0381x over previous
//
#include <hip/hip_runtime.h>

#define N_NODES 100000
#define NUM_TYPES 8
#define FACTOR 0.125f      // 1/sqrt(64)

#define S_CHUNK 25600      // nodes per chunk; 25600*4B = 100 KB LDS bins
#define C_CHUNKS 4         // 4*25600 = 102400 >= 100000
#define THR 1024
#define B_TARGET 64        // segments per chunk -> grid = 4*64 = 256 blocks (1/CU)

// ---------- Kernel 1: pre-pass, val[i] = eng[i]*scales[t[c],t[n]]*FACTOR ----------
// No LDS staging of atom_type (round-2's occupancy trap): the 400 KB table is
// L2-resident; 12.8M random 4B gathers overlap the 103 MB stream at full
// occupancy (16 VGPR, tiny LDS, 2048 blocks).
__global__ __launch_bounds__(256) void edge_val_kernel(
    const int* __restrict__ centers,
    const int* __restrict__ neighbors,
    const float* __restrict__ eng,
    const int* __restrict__ atom_type,
    const float* __restrict__ scales,
    float* __restrict__ vals,
    int E)
{
    __shared__ float s_scales[NUM_TYPES * NUM_TYPES];
    if (threadIdx.x < NUM_TYPES * NUM_TYPES)
        s_scales[threadIdx.x] = scales[threadIdx.x] * FACTOR;   // fold FACTOR
    __syncthreads();

    const int n4 = E >> 2;
    const int stride = gridDim.x * blockDim.x;

    for (int i = blockIdx.x * blockDim.x + threadIdx.x; i < n4; i += stride) {
        int4   cc = ((const int4*)centers)[i];
        int4   nn = ((const int4*)neighbors)[i];
        float4 e  = ((const float4*)eng)[i];
        float4 v;
        v.x = e.x * s_scales[atom_type[cc.x] * NUM_TYPES + atom_type[nn.x]];
        v.y = e.y * s_scales[atom_type[cc.y] * NUM_TYPES + atom_type[nn.y]];
        v.z = e.z * s_scales[atom_type[cc.z] * NUM_TYPES + atom_type[nn.z]];
        v.w = e.w * s_scales[atom_type[cc.w] * NUM_TYPES + atom_type[nn.w]];
        ((float4*)vals)[i] = v;
    }
    // tail (E % 4)
    for (int i = (n4 << 2) + blockIdx.x * blockDim.x + threadIdx.x; i < E; i += stride)
        vals[i] = eng[i] * s_scales[atom_type[centers[i]] * NUM_TYPES + atom_type[neighbors[i]]];
}

// ---------- Kernel 2: chunk-sum over (centers, vals) — lean 8B/edge sweep ----------
// Block (c,b): scans edge segment b; in-chunk edges accumulate into 100KB LDS
// bins. c = blockIdx % 4 -> the 4 chunks of a segment dispatch adjacently and
// sweep the SAME cache lines simultaneously (L2/L3 absorbs the 4x re-read).
// Traffic-bound (round 6), so 1 block/CU with max-size bins is the right trade.
__global__ __launch_bounds__(THR) void chunk_sum_kernel(
    const int* __restrict__ centers,
    const float* __restrict__ vals,
    float* __restrict__ partials,          // [C_CHUNKS][B][S_CHUNK]
    int E, int B)
{
    __shared__ __align__(16) float bins[S_CHUNK];

    const int c = blockIdx.x % C_CHUNKS;   // chunk (fast-varying -> co-scheduled)
    const int b = blockIdx.x / C_CHUNKS;   // edge segment

    float4* bins4 = (float4*)bins;
    for (int j = threadIdx.x; j < S_CHUNK / 4; j += THR)
        bins4[j] = make_float4(0.f, 0.f, 0.f, 0.f);
    __syncthreads();

    const int base = c * S_CHUNK;
    const int n4 = E >> 2;

    for (int i = b * THR + (int)threadIdx.x; i < n4; i += B * THR) {
        int4   cc = ((const int4*)centers)[i];
        float4 v  = ((const float4*)vals)[i];

        unsigned j0 = (unsigned)(cc.x - base);
        unsigned j1 = (unsigned)(cc.y - base);
        unsigned j2 = (unsigned)(cc.z - base);
        unsigned j3 = (unsigned)(cc.w - base);

        if (j0 < S_CHUNK) atomicAdd(&bins[j0], v.x);
        if (j1 < S_CHUNK) atomicAdd(&bins[j1], v.y);
        if (j2 < S_CHUNK) atomicAdd(&bins[j2], v.z);
        if (j3 < S_CHUNK) atomicAdd(&bins[j3], v.w);
    }

    // tail (E % 4) — dead for E = 6,400,000; handled by segment b==0 of each chunk
    if (b == 0) {
        for (int i = (n4 << 2) + (int)threadIdx.x; i < E; i += THR) {
            unsigned j = (unsigned)(centers[i] - base);
            if (j < S_CHUNK) atomicAdd(&bins[j], vals[i]);
        }
    }

    __syncthreads();
    float4* dst4 = (float4*)(partials + ((size_t)c * B + b) * S_CHUNK);
    for (int j = threadIdx.x; j < S_CHUNK / 4; j += THR) dst4[j] = bins4[j];
}

// ---------- Kernel 3: reduce segment partials (float4) ----------
__global__ __launch_bounds__(256) void reduce_kernel(
    const float* __restrict__ partials, float* __restrict__ out, int B, int N4)
{
    int t = blockIdx.x * blockDim.x + threadIdx.x;
    if (t >= N4) return;
    int n = t * 4;
    int c = n / S_CHUNK;
    int j = n - c * S_CHUNK;
    const float4* p = (const float4*)(partials + ((size_t)c * B) * S_CHUNK + j);
    float4 s = make_float4(0.f, 0.f, 0.f, 0.f);
    for (int b = 0; b < B; ++b) {
        float4 v = p[(size_t)b * (S_CHUNK / 4)];
        s.x += v.x; s.y += v.y; s.z += v.z; s.w += v.w;
    }
    ((float4*)out)[t] = s;
}

__global__ __launch_bounds__(256) void reduce_scalar_kernel(
    const float* __restrict__ partials, float* __restrict__ out, int B, int N)
{
    int n = blockIdx.x * blockDim.x + threadIdx.x;
    if (n >= N) return;
    int c = n / S_CHUNK;
    int j = n - c * S_CHUNK;
    const float* p = partials + ((size_t)c * B) * S_CHUNK + j;
    float s = 0.0f;
    for (int b = 0; b < B; ++b) s += p[(size_t)b * S_CHUNK];
    out[n] = s;
}

// ---------- Fallback (tiny workspace only): direct atomic scatter ----------
__global__ __launch_bounds__(256) void edge_sum_atomic_kernel(
    const int* __restrict__ centers, const int* __restrict__ neighbors,
    const float* __restrict__ eng, const int* __restrict__ atom_type,
    const float* __restrict__ scales, float* __restrict__ out, int E)
{
    __shared__ float s_scales[NUM_TYPES * NUM_TYPES];
    if (threadIdx.x < NUM_TYPES * NUM_TYPES) s_scales[threadIdx.x] = scales[threadIdx.x];
    __syncthreads();
    int tid = blockIdx.x * blockDim.x + threadIdx.x;
    int stride = gridDim.x * blockDim.x;
    for (int i = tid; i < E; i += stride) {
        int cn = centers[i];
        float v = eng[i] * s_scales[atom_type[cn] * NUM_TYPES + atom_type[neighbors[i]]] * FACTOR;
        unsafeAtomicAdd(&out[cn], v);
    }
}

extern "C" void kernel_launch(void* const* d_in, const int* in_sizes, int n_in,
                              void* d_out, int out_size, void* d_ws, size_t ws_size,
                              hipStream_t stream) {
    const int E = in_sizes[1];  // edge_eng element count
    const int N = in_sizes[2];  // atom_type element count
    const int* edge_index = (const int*)d_in[0];   // [2, E]
    const float* edge_eng = (const float*)d_in[1]; // [E, 1]
    const int* atom_type = (const int*)d_in[2];    // [N, 1]
    const float* scales = (const float*)d_in[3];   // [T, T]
    float* out = (float*)d_out;

    const int* centers = edge_index;
    const int* neighbors = edge_index + E;

    // ws layout: [vals: E floats][partials: C*B*S_CHUNK floats]
    auto al = [](size_t x) { return (x + 255) & ~(size_t)255; };
    size_t vals_sz = al((size_t)E * sizeof(float));               // 25.6 MB
    size_t per_b   = (size_t)C_CHUNKS * S_CHUNK * sizeof(float);  // 409.6 KB per segment

    int B = 0;
    if (N <= C_CHUNKS * S_CHUNK && ws_size > vals_sz)
        B = (int)((ws_size - vals_sz) / per_b);
    if (B > B_TARGET) B = B_TARGET;

    if (B >= 8) {
        float* vals     = (float*)d_ws;
        float* partials = (float*)((char*)d_ws + vals_sz);
        edge_val_kernel<<<2048, 256, 0, stream>>>(
            centers, neighbors, edge_eng, atom_type, scales, vals, E);
        chunk_sum_kernel<<<C_CHUNKS * B, THR, 0, stream>>>(
            centers, vals, partials, E, B);
        if ((N & 3) == 0)
            reduce_kernel<<<(N / 4 + 255) / 256, 256, 0, stream>>>(partials, out, B, N / 4);
        else
            reduce_scalar_kernel<<<(N + 255) / 256, 256, 0, stream>>>(partials, out, B, N);
    } else {
        hipMemsetAsync(d_out, 0, (size_t)out_size * sizeof(float), stream);
        edge_sum_atomic_kernel<<<2048, 256, 0, stream>>>(
            centers, neighbors, edge_eng, atom_type, scales, out, E);
    }
}

// Round 8
// 176.702 us; speedup vs baseline: 1.2105x; 1.1660x over previous
//
#include <hip/hip_runtime.h>

#define N_NODES 100000
#define NUM_TYPES 8
#define FACTOR 0.125f      // 1/sqrt(64)

#define S_CHUNK 25600      // nodes per chunk; bins 100 KB + ctt 25 KB = 125.3 KB LDS
#define C_CHUNKS 4         // 4*25600 = 102400 >= 100000
#define THR 1024
#define B_TARGET 64        // grid = 4*64 = 256 blocks (1/CU); traffic-bound so 1 blk/CU ok

// ---------- Kernel 0: pack atom_type to u8 (100 KB table) ----------
// Shrinks the gather target 4x: 64 nodes per 64B line -> high L1 hit rate in the
// fused pass. Pads to C*S with zeros so staging needs no bounds checks.
__global__ __launch_bounds__(256) void type_pack_kernel(
    const int* __restrict__ atom_type, unsigned char* __restrict__ tt, int N)
{
    int i = blockIdx.x * blockDim.x + threadIdx.x;
    if (i < C_CHUNKS * S_CHUNK)
        tt[i] = (i < N) ? (unsigned char)atom_type[i] : 0;
}

// ---------- Kernel 1: fused chunk-sum ----------
// Block (c,b): sweeps edge segment b; edges with center in chunk c accumulate
// eng*scale into 100 KB LDS bins. Gathers happen once per edge globally (guarded).
// Center type: ds_read_u8 from the LDS-staged 25 KB chunk window (random u8 ->
// ~2 lanes/bank, free). Neighbor type: global u8 gather into the 100 KB table
// (L1-friendly since center traffic no longer competes for L1).
// c = blockIdx % 4 -> chunks of a segment dispatch adjacently and sweep the SAME
// cache lines simultaneously (L2/L3 absorbs the 4x logical re-read — round 5).
__global__ __launch_bounds__(THR) void fused_chunk_sum_kernel(
    const int* __restrict__ centers,
    const int* __restrict__ neighbors,
    const float* __restrict__ eng,
    const unsigned char* __restrict__ tt,  // [C*S] u8 types (padded)
    const float* __restrict__ scales,
    float* __restrict__ partials,          // [C_CHUNKS][B][S_CHUNK]
    int E, int B)
{
    __shared__ __align__(16) float bins[S_CHUNK];
    __shared__ __align__(4) unsigned char ctt[S_CHUNK];   // chunk's center types
    __shared__ float s_scales[NUM_TYPES * NUM_TYPES];

    const int c = blockIdx.x % C_CHUNKS;   // chunk (fast-varying -> co-scheduled)
    const int b = blockIdx.x / C_CHUNKS;   // edge segment
    const int base = c * S_CHUNK;

    if (threadIdx.x < NUM_TYPES * NUM_TYPES)
        s_scales[threadIdx.x] = scales[threadIdx.x] * FACTOR;   // fold FACTOR

    float4* bins4 = (float4*)bins;
    for (int j = threadIdx.x; j < S_CHUNK / 4; j += THR)
        bins4[j] = make_float4(0.f, 0.f, 0.f, 0.f);
    // stage center-type window (S_CHUNK % 4 == 0, base % 4 == 0 -> uint copies)
    {
        const unsigned* src = (const unsigned*)(tt + base);
        unsigned* dst = (unsigned*)ctt;
        for (int j = threadIdx.x; j < S_CHUNK / 4; j += THR) dst[j] = src[j];
    }
    __syncthreads();

    const int n4 = E >> 2;

    for (int i = b * THR + (int)threadIdx.x; i < n4; i += B * THR) {
        int4   cc = ((const int4*)centers)[i];
        int4   nn = ((const int4*)neighbors)[i];
        float4 e  = ((const float4*)eng)[i];

        unsigned j0 = (unsigned)(cc.x - base);
        unsigned j1 = (unsigned)(cc.y - base);
        unsigned j2 = (unsigned)(cc.z - base);
        unsigned j3 = (unsigned)(cc.w - base);

        if (j0 < S_CHUNK)
            atomicAdd(&bins[j0], e.x * s_scales[(int)ctt[j0] * NUM_TYPES + (int)tt[nn.x]]);
        if (j1 < S_CHUNK)
            atomicAdd(&bins[j1], e.y * s_scales[(int)ctt[j1] * NUM_TYPES + (int)tt[nn.y]]);
        if (j2 < S_CHUNK)
            atomicAdd(&bins[j2], e.z * s_scales[(int)ctt[j2] * NUM_TYPES + (int)tt[nn.z]]);
        if (j3 < S_CHUNK)
            atomicAdd(&bins[j3], e.w * s_scales[(int)ctt[j3] * NUM_TYPES + (int)tt[nn.w]]);
    }

    // tail (E % 4) — dead for E = 6,400,000; handled by segment b==0 of each chunk
    if (b == 0) {
        for (int i = (n4 << 2) + (int)threadIdx.x; i < E; i += THR) {
            int cn = centers[i];
            unsigned j = (unsigned)(cn - base);
            if (j < S_CHUNK)
                atomicAdd(&bins[j], eng[i] * s_scales[(int)ctt[j] * NUM_TYPES + (int)tt[neighbors[i]]]);
        }
    }

    __syncthreads();
    float4* dst4 = (float4*)(partials + ((size_t)c * B + b) * S_CHUNK);
    for (int j = threadIdx.x; j < S_CHUNK / 4; j += THR) dst4[j] = bins4[j];
}

// ---------- Kernel 2: reduce segment partials (float4) ----------
__global__ __launch_bounds__(256) void reduce_kernel(
    const float* __restrict__ partials, float* __restrict__ out, int B, int N4)
{
    int t = blockIdx.x * blockDim.x + threadIdx.x;
    if (t >= N4) return;
    int n = t * 4;
    int c = n / S_CHUNK;
    int j = n - c * S_CHUNK;
    const float4* p = (const float4*)(partials + ((size_t)c * B) * S_CHUNK + j);
    float4 s = make_float4(0.f, 0.f, 0.f, 0.f);
    for (int b = 0; b < B; ++b) {
        float4 v = p[(size_t)b * (S_CHUNK / 4)];
        s.x += v.x; s.y += v.y; s.z += v.z; s.w += v.w;
    }
    ((float4*)out)[t] = s;
}

__global__ __launch_bounds__(256) void reduce_scalar_kernel(
    const float* __restrict__ partials, float* __restrict__ out, int B, int N)
{
    int n = blockIdx.x * blockDim.x + threadIdx.x;
    if (n >= N) return;
    int c = n / S_CHUNK;
    int j = n - c * S_CHUNK;
    const float* p = partials + ((size_t)c * B) * S_CHUNK + j;
    float s = 0.0f;
    for (int b = 0; b < B; ++b) s += p[(size_t)b * S_CHUNK];
    out[n] = s;
}

// ---------- Fallback (tiny workspace only): direct atomic scatter ----------
__global__ __launch_bounds__(256) void edge_sum_atomic_kernel(
    const int* __restrict__ centers, const int* __restrict__ neighbors,
    const float* __restrict__ eng, const int* __restrict__ atom_type,
    const float* __restrict__ scales, float* __restrict__ out, int E)
{
    __shared__ float s_scales[NUM_TYPES * NUM_TYPES];
    if (threadIdx.x < NUM_TYPES * NUM_TYPES) s_scales[threadIdx.x] = scales[threadIdx.x];
    __syncthreads();
    int tid = blockIdx.x * blockDim.x + threadIdx.x;
    int stride = gridDim.x * blockDim.x;
    for (int i = tid; i < E; i += stride) {
        int cn = centers[i];
        float v = eng[i] * s_scales[atom_type[cn] * NUM_TYPES + atom_type[neighbors[i]]] * FACTOR;
        unsafeAtomicAdd(&out[cn], v);
    }
}

extern "C" void kernel_launch(void* const* d_in, const int* in_sizes, int n_in,
                              void* d_out, int out_size, void* d_ws, size_t ws_size,
                              hipStream_t stream) {
    const int E = in_sizes[1];  // edge_eng element count
    const int N = in_sizes[2];  // atom_type element count
    const int* edge_index = (const int*)d_in[0];   // [2, E]
    const float* edge_eng = (const float*)d_in[1]; // [E, 1]
    const int* atom_type = (const int*)d_in[2];    // [N, 1]
    const float* scales = (const float*)d_in[3];   // [T, T]
    float* out = (float*)d_out;

    const int* centers = edge_index;
    const int* neighbors = edge_index + E;

    // ws layout: [tt: C*S u8 (aligned)][partials: C*B*S_CHUNK floats]
    auto al = [](size_t x) { return (x + 255) & ~(size_t)255; };
    size_t tt_sz  = al((size_t)C_CHUNKS * S_CHUNK);               // 100 KB
    size_t per_b  = (size_t)C_CHUNKS * S_CHUNK * sizeof(float);   // 409.6 KB per segment

    int B = 0;
    if (N <= C_CHUNKS * S_CHUNK && ws_size > tt_sz)
        B = (int)((ws_size - tt_sz) / per_b);
    if (B > B_TARGET) B = B_TARGET;

    if (B >= 8) {
        unsigned char* tt = (unsigned char*)d_ws;
        float* partials   = (float*)((char*)d_ws + tt_sz);
        type_pack_kernel<<<(C_CHUNKS * S_CHUNK + 255) / 256, 256, 0, stream>>>(
            atom_type, tt, N);
        fused_chunk_sum_kernel<<<C_CHUNKS * B, THR, 0, stream>>>(
            centers, neighbors, edge_eng, tt, scales, partials, E, B);
        if ((N & 3) == 0)
            reduce_kernel<<<(N / 4 + 255) / 256, 256, 0, stream>>>(partials, out, B, N / 4);
        else
            reduce_scalar_kernel<<<(N + 255) / 256, 256, 0, stream>>>(partials, out, B, N);
    } else {
        hipMemsetAsync(d_out, 0, (size_t)out_size * sizeof(float), stream);
        edge_sum_atomic_kernel<<<2048, 256, 0, stream>>>(
            centers, neighbors, edge_eng, atom_type, scales, out, E);
    }
}

// Round 10
// 167.320 us; speedup vs baseline: 1.2784x; 1.0561x over previous
//
#include <hip/hip_runtime.h>

#define N_NODES 100000
#define NUM_TYPES 8
#define FACTOR 0.125f      // 1/sqrt(64)

#define S_CHUNK 25600      // nodes per chunk; bins 100 KB + ctt 25 KB = 125.3 KB LDS
#define C_CHUNKS 4         // 4*25600 = 102400 >= 100000
#define THR 1024
#define B_TARGET 64        // grid = 4*64 = 256 blocks (1/CU)
#define NXCD 8             // MI355X XCD count; blockIdx % 8 ~ XCD under round-robin

// ---------- Kernel 0: pack atom_type to u8 (100 KB table) ----------
__global__ __launch_bounds__(256) void type_pack_kernel(
    const int* __restrict__ atom_type, unsigned char* __restrict__ tt, int N)
{
    int i = blockIdx.x * blockDim.x + threadIdx.x;
    if (i < C_CHUNKS * S_CHUNK)
        tt[i] = (i < N) ? (unsigned char)atom_type[i] : 0;
}

// ---------- Kernel 1: fused chunk-sum, XCD-local chunk grouping ----------
// Mapping: x = blk & 7 (XCD), o = blk >> 3, chunk c = o & 3,
// segment b = x*(B/8) + (o>>2). The 4 chunk-blocks of a segment thus land on
// the SAME XCD (consecutive dispatch, same progress rate) and sweep the same
// edge lines: each line is HBM-fetched once into that XCD's 4 MB L2 and served
// 3x from L2 — vs round 8's mapping where they sat on 4 different XCDs and
// only L3 (partially) absorbed the 4x re-read (FETCH stuck at 150 MB).
// Center type: ds_read_u8 from the LDS-staged 25 KB window. Neighbor type:
// global u8 gather in the 100 KB packed table (L1/L2-friendly).
__global__ __launch_bounds__(THR) void fused_chunk_sum_kernel(
    const int* __restrict__ centers,
    const int* __restrict__ neighbors,
    const float* __restrict__ eng,
    const unsigned char* __restrict__ tt,  // [C*S] u8 types (padded)
    const float* __restrict__ scales,
    float* __restrict__ partials,          // [C_CHUNKS][B][S_CHUNK]
    int E, int B)
{
    __shared__ __align__(16) float bins[S_CHUNK];
    __shared__ __align__(4) unsigned char ctt[S_CHUNK];   // chunk's center types
    __shared__ float s_scales[NUM_TYPES * NUM_TYPES];

    const int x = blockIdx.x & (NXCD - 1);   // XCD id (round-robin dispatch)
    const int o = blockIdx.x >> 3;           // ordinal within XCD
    const int c = o & 3;                     // chunk
    const int b = x * (B >> 3) + (o >> 2);   // edge segment (B % 8 == 0)
    const int base = c * S_CHUNK;

    if (threadIdx.x < NUM_TYPES * NUM_TYPES)
        s_scales[threadIdx.x] = scales[threadIdx.x] * FACTOR;   // fold FACTOR

    float4* bins4 = (float4*)bins;
    for (int j = threadIdx.x; j < S_CHUNK / 4; j += THR)
        bins4[j] = make_float4(0.f, 0.f, 0.f, 0.f);
    // stage center-type window (S_CHUNK % 4 == 0, base % 4 == 0 -> uint copies)
    {
        const unsigned* src = (const unsigned*)(tt + base);
        unsigned* dst = (unsigned*)ctt;
        for (int j = threadIdx.x; j < S_CHUNK / 4; j += THR) dst[j] = src[j];
    }
    __syncthreads();

    const int n4 = E >> 2;

    for (int i = b * THR + (int)threadIdx.x; i < n4; i += B * THR) {
        int4   cc = ((const int4*)centers)[i];
        int4   nn = ((const int4*)neighbors)[i];
        float4 e  = ((const float4*)eng)[i];

        unsigned j0 = (unsigned)(cc.x - base);
        unsigned j1 = (unsigned)(cc.y - base);
        unsigned j2 = (unsigned)(cc.z - base);
        unsigned j3 = (unsigned)(cc.w - base);

        if (j0 < S_CHUNK)
            atomicAdd(&bins[j0], e.x * s_scales[(int)ctt[j0] * NUM_TYPES + (int)tt[nn.x]]);
        if (j1 < S_CHUNK)
            atomicAdd(&bins[j1], e.y * s_scales[(int)ctt[j1] * NUM_TYPES + (int)tt[nn.y]]);
        if (j2 < S_CHUNK)
            atomicAdd(&bins[j2], e.z * s_scales[(int)ctt[j2] * NUM_TYPES + (int)tt[nn.z]]);
        if (j3 < S_CHUNK)
            atomicAdd(&bins[j3], e.w * s_scales[(int)ctt[j3] * NUM_TYPES + (int)tt[nn.w]]);
    }

    // tail (E % 4) — dead for E = 6,400,000; handled by segment b==0 of each chunk
    // (b==0 occurs once per chunk: blocks 0,8,16,24 are x=0,o=0..3 -> c=0..3, b=0)
    if (b == 0) {
        for (int i = (n4 << 2) + (int)threadIdx.x; i < E; i += THR) {
            int cn = centers[i];
            unsigned j = (unsigned)(cn - base);
            if (j < S_CHUNK)
                atomicAdd(&bins[j], eng[i] * s_scales[(int)ctt[j] * NUM_TYPES + (int)tt[neighbors[i]]]);
        }
    }

    __syncthreads();
    float4* dst4 = (float4*)(partials + ((size_t)c * B + b) * S_CHUNK);
    for (int j = threadIdx.x; j < S_CHUNK / 4; j += THR) dst4[j] = bins4[j];
}

// ---------- Kernel 2: reduce segment partials (float4) ----------
__global__ __launch_bounds__(256) void reduce_kernel(
    const float* __restrict__ partials, float* __restrict__ out, int B, int N4)
{
    int t = blockIdx.x * blockDim.x + threadIdx.x;
    if (t >= N4) return;
    int n = t * 4;
    int c = n / S_CHUNK;
    int j = n - c * S_CHUNK;
    const float4* p = (const float4*)(partials + ((size_t)c * B) * S_CHUNK + j);
    float4 s = make_float4(0.f, 0.f, 0.f, 0.f);
    for (int b = 0; b < B; ++b) {
        float4 v = p[(size_t)b * (S_CHUNK / 4)];
        s.x += v.x; s.y += v.y; s.z += v.z; s.w += v.w;
    }
    ((float4*)out)[t] = s;
}

__global__ __launch_bounds__(256) void reduce_scalar_kernel(
    const float* __restrict__ partials, float* __restrict__ out, int B, int N)
{
    int n = blockIdx.x * blockDim.x + threadIdx.x;
    if (n >= N) return;
    int c = n / S_CHUNK;
    int j = n - c * S_CHUNK;
    const float* p = partials + ((size_t)c * B) * S_CHUNK + j;
    float s = 0.0f;
    for (int b = 0; b < B; ++b) s += p[(size_t)b * S_CHUNK];
    out[n] = s;
}

// ---------- Fallback (tiny workspace only): direct atomic scatter ----------
__global__ __launch_bounds__(256) void edge_sum_atomic_kernel(
    const int* __restrict__ centers, const int* __restrict__ neighbors,
    const float* __restrict__ eng, const int* __restrict__ atom_type,
    const float* __restrict__ scales, float* __restrict__ out, int E)
{
    __shared__ float s_scales[NUM_TYPES * NUM_TYPES];
    if (threadIdx.x < NUM_TYPES * NUM_TYPES) s_scales[threadIdx.x] = scales[threadIdx.x];
    __syncthreads();
    int tid = blockIdx.x * blockDim.x + threadIdx.x;
    int stride = gridDim.x * blockDim.x;
    for (int i = tid; i < E; i += stride) {
        int cn = centers[i];
        float v = eng[i] * s_scales[atom_type[cn] * NUM_TYPES + atom_type[neighbors[i]]] * FACTOR;
        unsafeAtomicAdd(&out[cn], v);
    }
}

extern "C" void kernel_launch(void* const* d_in, const int* in_sizes, int n_in,
                              void* d_out, int out_size, void* d_ws, size_t ws_size,
                              hipStream_t stream) {
    const int E = in_sizes[1];  // edge_eng element count
    const int N = in_sizes[2];  // atom_type element count
    const int* edge_index = (const int*)d_in[0];   // [2, E]
    const float* edge_eng = (const float*)d_in[1]; // [E, 1]
    const int* atom_type = (const int*)d_in[2];    // [N, 1]
    const float* scales = (const float*)d_in[3];   // [T, T]
    float* out = (float*)d_out;

    const int* centers = edge_index;
    const int* neighbors = edge_index + E;

    // ws layout: [tt: C*S u8 (aligned)][partials: C*B*S_CHUNK floats]
    auto al = [](size_t x) { return (x + 255) & ~(size_t)255; };
    size_t tt_sz  = al((size_t)C_CHUNKS * S_CHUNK);               // 100 KB
    size_t per_b  = (size_t)C_CHUNKS * S_CHUNK * sizeof(float);   // 409.6 KB per segment

    int B = 0;
    if (N <= C_CHUNKS * S_CHUNK && ws_size > tt_sz)
        B = (int)((ws_size - tt_sz) / per_b);
    if (B > B_TARGET) B = B_TARGET;
    B &= ~7;   // XCD-local mapping requires B % 8 == 0

    if (B >= 8) {
        unsigned char* tt = (unsigned char*)d_ws;
        float* partials   = (float*)((char*)d_ws + tt_sz);
        type_pack_kernel<<<(C_CHUNKS * S_CHUNK + 255) / 256, 256, 0, stream>>>(
            atom_type, tt, N);
        fused_chunk_sum_kernel<<<C_CHUNKS * B, THR, 0, stream>>>(
            centers, neighbors, edge_eng, tt, scales, partials, E, B);
        if ((N & 3) == 0)
            reduce_kernel<<<(N / 4 + 255) / 256, 256, 0, stream>>>(partials, out, B, N / 4);
        else
            reduce_scalar_kernel<<<(N + 255) / 256, 256, 0, stream>>>(partials, out, B, N);
    } else {
        hipMemsetAsync(d_out, 0, (size_t)out_size * sizeof(float), stream);
        edge_sum_atomic_kernel<<<2048, 256, 0, stream>>>(
            centers, neighbors, edge_eng, atom_type, scales, out, E);
    }
}